// Round 9
// baseline (648.277 us; speedup 1.0000x reference)
//
#include <hip/hip_runtime.h>

// RepformerLayer attention: nf=1, nloc=1024, nnei=128, ng2=nd=32, nh=4. f32 I/O.
// 4 blocks/CU design: LDS 37.4 KB, VGPR<=128 (__launch_bounds__(256,4)).
// No weight LDS: Bq (dbl-bf16) and W2 (single) refolded per strip-head,
// wave-privately, through per-wave scratch. XOR-swizzled scatter stores
// (2-way banks). Softmax fused with P-pack + PV on UNNORMALIZED P; row
// normalization applied to Ta/ohl after the k-reduction. may_alias types
// replace asm fences (true LDS deps ordered; global gathers hoistable).

typedef __bf16 v8bf __attribute__((ext_vector_type(8)));
typedef float  v4f  __attribute__((ext_vector_type(4)));
typedef unsigned short u16x4 __attribute__((ext_vector_type(4)));
typedef unsigned short u16a  __attribute__((may_alias));
typedef v8bf  v8bfa  __attribute__((may_alias));
typedef u16x4 u16x4a __attribute__((may_alias));

__device__ __forceinline__ float b2f(unsigned short b) {
    union { unsigned u; float f; } x; x.u = ((unsigned)b) << 16; return x.f;
}
__device__ __forceinline__ unsigned short f2b(float f) {
    union { float f; unsigned u; } x; x.f = f;
    unsigned r = x.u + 0x7FFFu + ((x.u >> 16) & 1u);
    return (unsigned short)(r >> 16);
}
struct HL { unsigned short hi, lo; };
__device__ __forceinline__ HL splitbf(float f) {
    HL r; r.hi = f2b(f); r.lo = f2b(f - b2f(r.hi)); return r;
}
union W8 { unsigned short u[8]; v8bf v; };

#define MF(a,b,c) __builtin_amdgcn_mfma_f32_16x16x32_bf16((a),(b),(c),0,0,0)

// LDS offsets (u16 units)
#define G2H 0        // [128][32] g2 hi
#define G2L 4096     // [128][32] g2 lo
#define G2T 8192     // [32][136] g2 hi transposed * ekv[k]
#define H2T 12544    // [4][128] bf16 * ekv[k], row 3 = zeros
#define PQ  13056    // [4 waves][1024] scratch: folds / q2 / P(x2) / T
#define SM_U16 17152 // 34304 B + 3072 B smf = 37376 B -> 4 blocks/CU

__global__ __launch_bounds__(256, 4) void repformer_kernel(
    const float* __restrict__ g2, const float* __restrict__ h2,
    const float* __restrict__ sw, const float* __restrict__ wqk,
    const float* __restrict__ wv, const float* __restrict__ wh,
    const float* __restrict__ bh, const float* __restrict__ weq,
    const int*   __restrict__ nmask, float* __restrict__ out)
{
    __shared__ __align__(16) unsigned short sm[SM_U16];
    __shared__ float smf[768];   // h2s[128][4] | sws[128] | es[128]
    float* h2s = smf;
    float* sws = smf + 512;
    float* es  = smf + 640;

    const int t    = threadIdx.x;
    const int i    = blockIdx.x;
    const int lane = t & 63;
    const int wv4  = t >> 6;
    const int quad = lane >> 4;
    const int n16  = lane & 15;
    const int swr  = ((n16 >> 2) ^ n16) & 3;       // row-swizzle for row==n16
    const int rblk = ((quad ^ swr) & 3) * 8;       // swizzled read block

    // ---------------- stage per-loc inputs ----------------
    {
        const float4* src = (const float4*)(g2 + (size_t)i * 4096);
        #pragma unroll
        for (int j = 0; j < 4; j++) {
            int idx = j * 256 + t;
            float4 v = src[idx];
            u16x4 ph, pl;
            HL a0 = splitbf(v.x); ph[0] = a0.hi; pl[0] = a0.lo;
            HL a1 = splitbf(v.y); ph[1] = a1.hi; pl[1] = a1.lo;
            HL a2 = splitbf(v.z); ph[2] = a2.hi; pl[2] = a2.lo;
            HL a3 = splitbf(v.w); ph[3] = a3.hi; pl[3] = a3.lo;
            *(u16x4a*)(sm + G2H + idx * 4) = ph;
            *(u16x4a*)(sm + G2L + idx * 4) = pl;
            int k = idx >> 3, c0 = (idx & 7) * 4;       // transpose hi copy
            ((u16a*)sm)[G2T + (c0 + 0) * 136 + k] = ph[0];
            ((u16a*)sm)[G2T + (c0 + 1) * 136 + k] = ph[1];
            ((u16a*)sm)[G2T + (c0 + 2) * 136 + k] = ph[2];
            ((u16a*)sm)[G2T + (c0 + 3) * 136 + k] = ph[3];
        }
    }
    for (int e = t; e < 384; e += 256) {
        float f = h2[(size_t)i * 384 + e];
        int k = e / 3, c = e - k * 3;
        h2s[k * 4 + c] = f;
        ((u16a*)sm)[H2T + c * 128 + k] = f2b(f);
    }
    if (t < 128) {
        ((u16a*)sm)[H2T + 384 + t] = 0;
        float s = sw[i * 128 + t];
        sws[t] = s;
        es[t]  = (nmask[i * 128 + t] != 0) ? s : 0.0f;
    }
    __syncthreads();
    // ---- fold ekv[k] into G2T / H2T columns ----
    {
        int kcol = t & 127;
        int c0 = (t >> 7) * 16;
        float ek = es[kcol];
        #pragma unroll
        for (int c = 0; c < 16; c++) {
            int idx = G2T + (c0 + c) * 136 + kcol;
            ((u16a*)sm)[idx] = f2b(b2f(((u16a*)sm)[idx]) * ek);
        }
        if (t < 128) {
            #pragma unroll
            for (int c = 0; c < 3; c++) {
                int idx = H2T + c * 128 + t;
                ((u16a*)sm)[idx] = f2b(b2f(((u16a*)sm)[idx]) * es[t]);
            }
        }
    }
    __syncthreads();

    const int hr = (n16 < 3) ? n16 : 3;
    u16a* scratch = (u16a*)(sm + PQ + wv4 * 1024);   // wave-private
    float weqf[4];
    #pragma unroll
    for (int hh = 0; hh < 4; hh++) weqf[hh] = weq[hh];
    float* outg = out;
    float* outh = out + 4194304;   // 1024*128*32
    float bias0 = bh[n16];
    float bias1 = bh[16 + n16];

    // =================== strips outer, heads inner (no barriers) ==========
    #pragma unroll
    for (int sl = 0; sl < 2; sl++) {
        int s = 2 * wv4 + sl;
        v8bf gfh = *(const v8bfa*)(sm + G2H + (s * 16 + n16) * 32 + quad * 8);
        v8bf gfl = *(const v8bfa*)(sm + G2L + (s * 16 + n16) * 32 + quad * 8);
        int qb = s * 16 + quad * 4;
        float swq[4], eqv[4], swk[8], htc[8][4];
        {
            float hq0[4], hq1[4], hq2[4];
            #pragma unroll
            for (int r = 0; r < 4; r++) {
                swq[r] = sws[qb + r]; eqv[r] = es[qb + r];
                hq0[r] = h2s[(qb + r) * 4 + 0] * 0.17677669529663687f;
                hq1[r] = h2s[(qb + r) * 4 + 1] * 0.17677669529663687f;
                hq2[r] = h2s[(qb + r) * 4 + 2] * 0.17677669529663687f;
            }
            #pragma unroll
            for (int kt = 0; kt < 8; kt++) {
                int kk = kt * 16 + n16;
                swk[kt] = sws[kk];
                float k0 = h2s[kk * 4 + 0], k1 = h2s[kk * 4 + 1], k2 = h2s[kk * 4 + 2];
                #pragma unroll
                for (int r = 0; r < 4; r++)
                    htc[kt][r] = fmaf(hq2[r], k2, fmaf(hq1[r], k1, hq0[r] * k0));
            }
        }
        v4f og0 = {0.f, 0.f, 0.f, 0.f}, og1 = og0, ohacc = og0;

        #pragma unroll
        for (int hd = 0; hd < 4; hd++) {
            v4f z = {0.f, 0.f, 0.f, 0.f};
            // ---- Bq refold (dbl-bf16): A=Wq[c][d], B=Wk[c'][d] -> C[c][c'] ----
            v4f cc[2][2];
            {
                W8 awh[2], awl[2], bwh[2], bwl[2];
                #pragma unroll
                for (int mt = 0; mt < 2; mt++)
                    #pragma unroll
                    for (int j = 0; j < 8; j++) {
                        HL q = splitbf(wqk[(mt * 16 + n16) * 256 + (quad * 8 + j) * 8 + hd]);
                        awh[mt].u[j] = q.hi; awl[mt].u[j] = q.lo;
                        HL k = splitbf(wqk[(mt * 16 + n16) * 256 + (quad * 8 + j) * 8 + 4 + hd]);
                        bwh[mt].u[j] = k.hi; bwl[mt].u[j] = k.lo;
                    }
                #pragma unroll
                for (int mt = 0; mt < 2; mt++)
                    #pragma unroll
                    for (int nt = 0; nt < 2; nt++)
                        cc[mt][nt] = MF(awh[mt].v, bwh[nt].v,
                                     MF(awl[mt].v, bwh[nt].v,
                                     MF(awh[mt].v, bwl[nt].v, z)));
            }
            // transposed b64 store hi: C[m][n] -> (row=n=c', col=m=c)
            #pragma unroll
            for (int mt = 0; mt < 2; mt++)
                #pragma unroll
                for (int nt = 0; nt < 2; nt++) {
                    u16x4 p;
                    p[0] = f2b(cc[mt][nt][0]); p[1] = f2b(cc[mt][nt][1]);
                    p[2] = f2b(cc[mt][nt][2]); p[3] = f2b(cc[mt][nt][3]);
                    *(u16x4a*)(scratch + (nt * 16 + n16) * 32 + ((mt * 16 + quad * 4) ^ (swr << 3))) = p;
                }
            v8bf bqh0 = *(const v8bfa*)(scratch + n16 * 32 + rblk);
            v8bf bqh1 = *(const v8bfa*)(scratch + (16 + n16) * 32 + rblk);
            #pragma unroll
            for (int mt = 0; mt < 2; mt++)
                #pragma unroll
                for (int nt = 0; nt < 2; nt++) {
                    u16x4 p;
                    #pragma unroll
                    for (int r = 0; r < 4; r++)
                        p[r] = f2b(cc[mt][nt][r] - b2f(f2b(cc[mt][nt][r])));
                    *(u16x4a*)(scratch + (nt * 16 + n16) * 32 + ((mt * 16 + quad * 4) ^ (swr << 3))) = p;
                }
            v8bf bql0 = *(const v8bfa*)(scratch + n16 * 32 + rblk);
            v8bf bql1 = *(const v8bfa*)(scratch + (16 + n16) * 32 + rblk);

            // ---- q2 = g2_strip @ M (3-term dbl-bf16); C[m=q][n=c'] ----
            v4f qc0 = MF(gfh, bqh0, MF(gfl, bqh0, MF(gfh, bql0, z)));
            v4f qc1 = MF(gfh, bqh1, MF(gfl, bqh1, MF(gfh, bql1, z)));
            #pragma unroll
            for (int r = 0; r < 4; r++) {
                int sw8 = ((quad ^ r) & 3) << 3;
                scratch[(quad * 4 + r) * 32 + (n16 ^ sw8)]        = f2b(qc0[r]);
                scratch[(quad * 4 + r) * 32 + ((16 + n16) ^ sw8)] = f2b(qc1[r]);
            }
            v8bf aqh = *(const v8bfa*)(scratch + n16 * 32 + rblk);
            #pragma unroll
            for (int r = 0; r < 4; r++) {
                int sw8 = ((quad ^ r) & 3) << 3;
                scratch[(quad * 4 + r) * 32 + (n16 ^ sw8)]        = f2b(qc0[r] - b2f(f2b(qc0[r])));
                scratch[(quad * 4 + r) * 32 + ((16 + n16) ^ sw8)] = f2b(qc1[r] - b2f(f2b(qc1[r])));
            }
            v8bf aql = *(const v8bfa*)(scratch + n16 * 32 + rblk);

            // ---- fused S -> softmax -> unnormalized P -> PV, per 32-key chunk --
            v4f Ta0 = z, Ta1 = z, ohl = z;
            float sum[4] = {0.f, 0.f, 0.f, 0.f};
            #pragma unroll
            for (int ks = 0; ks < 4; ks++) {
                u16a* Pb = scratch + (ks & 1) * 512;
                #pragma unroll
                for (int n2 = 0; n2 < 2; n2++) {
                    int kt = ks * 2 + n2;
                    v8bf bkh = *(const v8bfa*)(sm + G2H + (kt * 16 + n16) * 32 + quad * 8);
                    v8bf bkl = *(const v8bfa*)(sm + G2L + (kt * 16 + n16) * 32 + quad * 8);
                    v4f sfv = MF(aqh, bkh, MF(aql, bkh, MF(aqh, bkl, z)));
                    float ssk = swk[kt];
                    #pragma unroll
                    for (int r = 0; r < 4; r++) {
                        float l = fmaf(fmaf(sfv[r], htc[kt][r], 20.0f), swq[r] * ssk, -20.0f);
                        float p = __expf(l);
                        sum[r] += p;
                        Pb[(quad * 4 + r) * 32 + ((n2 * 16 + n16) ^ (((quad ^ r) & 3) << 3))]
                            = f2b(p * htc[kt][r]);
                    }
                }
                v8bf ap = *(const v8bfa*)(Pb + n16 * 32 + rblk);
                v8bf bg0 = *(const v8bfa*)(sm + G2T + n16 * 136 + ks * 32 + quad * 8);
                v8bf bg1 = *(const v8bfa*)(sm + G2T + (16 + n16) * 136 + ks * 32 + quad * 8);
                Ta0 = MF(ap, bg0, Ta0);
                Ta1 = MF(ap, bg1, Ta1);
                v8bf bh2 = *(const v8bfa*)(sm + H2T + hr * 128 + ks * 32 + quad * 8);
                ohl = MF(ap, bh2, ohl);
            }
            // ---- denominators + row factors ----
            float fac[4];
            #pragma unroll
            for (int r = 0; r < 4; r++) {
                float sc = sum[r];
                sc += __shfl_xor(sc, 1, 64);
                sc += __shfl_xor(sc, 2, 64);
                sc += __shfl_xor(sc, 4, 64);
                sc += __shfl_xor(sc, 8, 64);
                fac[r] = eqv[r] * 3.2659863237109f * __builtin_amdgcn_rcpf(sc);
            }
            #pragma unroll
            for (int r = 0; r < 4; r++) ohacc[r] += weqf[hd] * fac[r] * ohl[r];

            // ---- W2 refold (single-bf16 inputs): A=Wv[c][g], B=Wh[g][o] ----
            {
                W8 vwh[2], hwh[2];
                #pragma unroll
                for (int mt = 0; mt < 2; mt++)
                    #pragma unroll
                    for (int j = 0; j < 8; j++) {
                        vwh[mt].u[j] = f2b(wv[(mt * 16 + n16) * 128 + (quad * 8 + j) * 4 + hd]);
                        hwh[mt].u[j] = f2b(wh[((quad * 8 + j) * 4 + hd) * 32 + mt * 16 + n16]);
                    }
                #pragma unroll
                for (int mt = 0; mt < 2; mt++)
                    #pragma unroll
                    for (int nt = 0; nt < 2; nt++) {
                        v4f c2 = MF(vwh[mt].v, hwh[nt].v, z);
                        u16x4 p;
                        p[0] = f2b(c2[0]); p[1] = f2b(c2[1]);
                        p[2] = f2b(c2[2]); p[3] = f2b(c2[3]);
                        *(u16x4a*)(scratch + (nt * 16 + n16) * 32 + ((mt * 16 + quad * 4) ^ (swr << 3))) = p;
                    }
            }
            v8bf w20 = *(const v8bfa*)(scratch + n16 * 32 + rblk);
            v8bf w21 = *(const v8bfa*)(scratch + (16 + n16) * 32 + rblk);

            // ---- T (normalized) roundtrip -> og += T @ W2 ----
            #pragma unroll
            for (int r = 0; r < 4; r++) {
                int sw8 = ((quad ^ r) & 3) << 3;
                scratch[(quad * 4 + r) * 32 + (n16 ^ sw8)]        = f2b(Ta0[r] * fac[r]);
                scratch[(quad * 4 + r) * 32 + ((16 + n16) ^ sw8)] = f2b(Ta1[r] * fac[r]);
            }
            v8bf aT = *(const v8bfa*)(scratch + n16 * 32 + rblk);
            og0 = MF(aT, w20, og0);
            og1 = MF(aT, w21, og1);
        }

        // ---- strip epilogue (f32 out) ----
        int qg = i * 128 + qb;
        #pragma unroll
        for (int r = 0; r < 4; r++) {
            outg[(size_t)(qg + r) * 32 + n16]      = og0[r] + bias0;
            outg[(size_t)(qg + r) * 32 + 16 + n16] = og1[r] + bias1;
        }
        if (n16 < 3) {
            #pragma unroll
            for (int r = 0; r < 4; r++)
                outh[(size_t)(qg + r) * 3 + n16] = ohacc[r];
        }
    }
}

extern "C" void kernel_launch(void* const* d_in, const int* in_sizes, int n_in,
                              void* d_out, int out_size, void* d_ws, size_t ws_size,
                              hipStream_t stream) {
    const float* g2  = (const float*)d_in[0];
    const float* h2  = (const float*)d_in[1];
    const float* sw  = (const float*)d_in[2];
    const float* wqk = (const float*)d_in[3];
    const float* wv  = (const float*)d_in[4];
    const float* wh  = (const float*)d_in[5];
    const float* bh  = (const float*)d_in[6];
    const float* weq = (const float*)d_in[7];
    const int*   nm  = (const int*)d_in[8];
    int nloc = in_sizes[0] / (128 * 32);   // 1024
    repformer_kernel<<<nloc, 256, 0, stream>>>(g2, h2, sw, wqk, wv, wh, bh, weq, nm, (float*)d_out);
}

// Round 10
// 248.339 us; speedup vs baseline: 2.6105x; 2.6105x over previous
//
#include <hip/hip_runtime.h>

// RepformerLayer attention: nf=1, nloc=1024, nnei=128, ng2=nd=32, nh=4. f32 I/O.
// Round-8 structure (95.6us) + 4-blocks/CU diet:
//  - Bq (M=WqWk^T, single-bf16) B-frags in 32 VGPRs for all 4 heads,
//    folded once in prologue (dbl-input 3-MFMA chain, rounded once).
//  - q2 keeps hi+lo double-bf16 via sequential single-buffer roundtrip.
//  - scratch stride 40 u16: scatter stores hit 2 bank phases (was 1).
//  - LDS 39.4 KB, launch_bounds(256,4) -> 4 blocks/CU, single wave-round.

typedef __bf16 v8bf __attribute__((ext_vector_type(8)));
typedef float  v4f  __attribute__((ext_vector_type(4)));
typedef unsigned short u16x4 __attribute__((ext_vector_type(4)));
typedef unsigned short u16a  __attribute__((may_alias));
typedef v8bf  v8bfa  __attribute__((may_alias));
typedef u16x4 u16x4a __attribute__((may_alias));

__device__ __forceinline__ float b2f(unsigned short b) {
    union { unsigned u; float f; } x; x.u = ((unsigned)b) << 16; return x.f;
}
__device__ __forceinline__ unsigned short f2b(float f) {
    union { float f; unsigned u; } x; x.f = f;
    unsigned r = x.u + 0x7FFFu + ((x.u >> 16) & 1u);
    return (unsigned short)(r >> 16);
}
struct HL { unsigned short hi, lo; };
__device__ __forceinline__ HL splitbf(float f) {
    HL r; r.hi = f2b(f); r.lo = f2b(f - b2f(r.hi)); return r;
}
union W8 { unsigned short u[8]; v8bf v; };

#define MF(a,b,c) __builtin_amdgcn_mfma_f32_16x16x32_bf16((a),(b),(c),0,0,0)

// LDS offsets (u16 units)
#define G2H 0        // [128][32] g2 hi
#define G2L 4096     // [128][32] g2 lo
#define G2T 8192     // [32][136] g2 hi transposed * ekv[k]; prologue: Bq temp
#define H2T 12544    // [4][128] bf16 * ekv[k], row 3 = zeros
#define PQ  13056    // [4 waves][32][40] scratch: q2 / P / T / W2 fold
#define SM_U16 18176 // 36352 B + 3072 B smf = 39424 B -> 4 blocks/CU

__global__ __launch_bounds__(256, 4) void repformer_kernel(
    const float* __restrict__ g2, const float* __restrict__ h2,
    const float* __restrict__ sw, const float* __restrict__ wqk,
    const float* __restrict__ wv, const float* __restrict__ wh,
    const float* __restrict__ bh, const float* __restrict__ weq,
    const int*   __restrict__ nmask, float* __restrict__ out)
{
    __shared__ __align__(16) unsigned short sm[SM_U16];
    __shared__ float smf[768];   // h2s[128][4] | sws[128] | es[128]
    float* h2s = smf;
    float* sws = smf + 512;
    float* es  = smf + 640;

    const int t    = threadIdx.x;
    const int i    = blockIdx.x;
    const int lane = t & 63;
    const int wv4  = t >> 6;
    const int quad = lane >> 4;
    const int n16  = lane & 15;
    const int h    = wv4;          // prologue fold: wave w -> head w

    // ---------------- stage per-loc inputs ----------------
    {
        const float4* src = (const float4*)(g2 + (size_t)i * 4096);
        #pragma unroll
        for (int j = 0; j < 4; j++) {
            int idx = j * 256 + t;
            float4 v = src[idx];
            u16x4 ph, pl;
            HL a0 = splitbf(v.x); ph[0] = a0.hi; pl[0] = a0.lo;
            HL a1 = splitbf(v.y); ph[1] = a1.hi; pl[1] = a1.lo;
            HL a2 = splitbf(v.z); ph[2] = a2.hi; pl[2] = a2.lo;
            HL a3 = splitbf(v.w); ph[3] = a3.hi; pl[3] = a3.lo;
            *(u16x4a*)(sm + G2H + idx * 4) = ph;
            *(u16x4a*)(sm + G2L + idx * 4) = pl;
        }
    }
    for (int e = t; e < 384; e += 256) {
        float f = h2[(size_t)i * 384 + e];
        int k = e / 3, c = e - k * 3;
        h2s[k * 4 + c] = f;
        ((u16a*)sm)[H2T + c * 128 + k] = f2b(f);
    }
    if (t < 128) {
        ((u16a*)sm)[H2T + 384 + t] = 0;
        float s = sw[i * 128 + t];
        sws[t] = s;
        es[t]  = (nmask[i * 128 + t] != 0) ? s : 0.0f;
    }
    __syncthreads();

    // ---- prologue Bq fold: wave w folds head w into G2T-temp (hi only) ----
    {
        u16a* temp = (u16a*)(sm + G2T + h * 1024);   // [32][32]
        W8 awh[2], awl[2], bwh[2], bwl[2];
        #pragma unroll
        for (int mt = 0; mt < 2; mt++)
            #pragma unroll
            for (int j = 0; j < 8; j++) {
                HL q = splitbf(wqk[(mt * 16 + n16) * 256 + (quad * 8 + j) * 8 + h]);     // Wq[c][d]
                awh[mt].u[j] = q.hi; awl[mt].u[j] = q.lo;
                HL k = splitbf(wqk[(mt * 16 + n16) * 256 + (quad * 8 + j) * 8 + 4 + h]); // Wk[c'][d]
                bwh[mt].u[j] = k.hi; bwl[mt].u[j] = k.lo;
            }
        v4f z = {0.f, 0.f, 0.f, 0.f};
        #pragma unroll
        for (int mt = 0; mt < 2; mt++)
            #pragma unroll
            for (int nt = 0; nt < 2; nt++) {
                // C[m=c][n=c'] = M[c][c'] (3-term dbl chain), store Bq[c'][c]
                v4f c1 = MF(awh[mt].v, bwh[nt].v,
                         MF(awl[mt].v, bwh[nt].v,
                         MF(awh[mt].v, bwl[nt].v, z)));
                u16x4 p;
                p[0] = f2b(c1[0]); p[1] = f2b(c1[1]); p[2] = f2b(c1[2]); p[3] = f2b(c1[3]);
                *(u16x4a*)(temp + (nt * 16 + n16) * 32 + mt * 16 + quad * 4) = p;
            }
    }
    __syncthreads();

    // ---- every wave: Bq B-frags for ALL heads -> 32 VGPRs ----
    v8bf bqf[4][2];
    #pragma unroll
    for (int hh = 0; hh < 4; hh++)
        #pragma unroll
        for (int nt = 0; nt < 2; nt++)
            bqf[hh][nt] = *(const v8bfa*)(sm + G2T + hh * 1024 + (nt * 16 + n16) * 32 + quad * 8);
    __syncthreads();   // temp reads done; G2T area free

    // ---- build G2T = g2hi^T * ekv (stride 136) + scale H2T by ekv ----
    #pragma unroll
    for (int j = 0; j < 4; j++) {
        int idx = j * 256 + t;
        int k = idx >> 3, c0 = (idx & 7) * 4;
        u16x4 v = *(const u16x4a*)(sm + G2H + k * 32 + c0);
        float ek = es[k];
        #pragma unroll
        for (int c = 0; c < 4; c++)
            ((u16a*)sm)[G2T + (c0 + c) * 136 + k] = f2b(b2f(v[c]) * ek);
    }
    if (t < 128) {
        #pragma unroll
        for (int c = 0; c < 3; c++) {
            int idx = H2T + c * 128 + t;
            ((u16a*)sm)[idx] = f2b(b2f(((u16a*)sm)[idx]) * es[t]);
        }
    }
    __syncthreads();

    const int hr = (n16 < 3) ? n16 : 3;
    u16a* scratch = (u16a*)(sm + PQ + wv4 * 1280);   // wave-private [32][40]
    float weqf[4];
    #pragma unroll
    for (int hh = 0; hh < 4; hh++) weqf[hh] = weq[hh];
    float* outg = out;
    float* outh = out + 4194304;   // 1024*128*32
    float bias0 = bh[n16];
    float bias1 = bh[16 + n16];

    // =================== strips outer, heads inner (no barriers) ==========
    #pragma unroll
    for (int sl = 0; sl < 2; sl++) {
        int s = 2 * wv4 + sl;
        v8bf gfh = *(const v8bfa*)(sm + G2H + (s * 16 + n16) * 32 + quad * 8);
        v8bf gfl = *(const v8bfa*)(sm + G2L + (s * 16 + n16) * 32 + quad * 8);
        int qb = s * 16 + quad * 4;
        float swq[4], eqv[4], swk[8], htc[8][4];
        {
            float hq0[4], hq1[4], hq2[4];
            #pragma unroll
            for (int r = 0; r < 4; r++) {
                swq[r] = sws[qb + r]; eqv[r] = es[qb + r];
                hq0[r] = h2s[(qb + r) * 4 + 0] * 0.17677669529663687f;
                hq1[r] = h2s[(qb + r) * 4 + 1] * 0.17677669529663687f;
                hq2[r] = h2s[(qb + r) * 4 + 2] * 0.17677669529663687f;
            }
            #pragma unroll
            for (int kt = 0; kt < 8; kt++) {
                int kk = kt * 16 + n16;
                swk[kt] = sws[kk];
                float k0 = h2s[kk * 4 + 0], k1 = h2s[kk * 4 + 1], k2 = h2s[kk * 4 + 2];
                #pragma unroll
                for (int r = 0; r < 4; r++)
                    htc[kt][r] = fmaf(hq2[r], k2, fmaf(hq1[r], k1, hq0[r] * k0));
            }
        }
        v4f og0 = {0.f, 0.f, 0.f, 0.f}, og1 = og0, ohacc = og0;

        #pragma unroll
        for (int hd = 0; hd < 4; hd++) {
            v4f z = {0.f, 0.f, 0.f, 0.f};
            // ---- q2 = g2_strip @ M (2-term: dbl g2 x single Bq-reg) ----
            v4f qc0 = MF(gfh, bqf[hd][0], MF(gfl, bqf[hd][0], z));
            v4f qc1 = MF(gfh, bqf[hd][1], MF(gfl, bqf[hd][1], z));
            asm volatile("" ::: "memory");
            #pragma unroll
            for (int r = 0; r < 4; r++) {
                scratch[(quad * 4 + r) * 40 + n16]      = f2b(qc0[r]);
                scratch[(quad * 4 + r) * 40 + 16 + n16] = f2b(qc1[r]);
            }
            asm volatile("" ::: "memory");
            v8bf aqh = *(const v8bfa*)(scratch + n16 * 40 + quad * 8);
            asm volatile("" ::: "memory");
            #pragma unroll
            for (int r = 0; r < 4; r++) {
                scratch[(quad * 4 + r) * 40 + n16]      = f2b(qc0[r] - b2f(f2b(qc0[r])));
                scratch[(quad * 4 + r) * 40 + 16 + n16] = f2b(qc1[r] - b2f(f2b(qc1[r])));
            }
            asm volatile("" ::: "memory");
            v8bf aql = *(const v8bfa*)(scratch + n16 * 40 + quad * 8);
            asm volatile("" ::: "memory");

            // ---- fused S -> softmax -> unnormalized P -> PV per 32-key chunk --
            v4f Ta0 = z, Ta1 = z, ohl = z;
            float sum[4] = {0.f, 0.f, 0.f, 0.f};
            #pragma unroll
            for (int ks = 0; ks < 4; ks++) {
                asm volatile("" ::: "memory");
                #pragma unroll
                for (int n2 = 0; n2 < 2; n2++) {
                    int kt = ks * 2 + n2;
                    v8bf bkh = *(const v8bfa*)(sm + G2H + (kt * 16 + n16) * 32 + quad * 8);
                    v8bf bkl = *(const v8bfa*)(sm + G2L + (kt * 16 + n16) * 32 + quad * 8);
                    v4f sfv = MF(aqh, bkh, MF(aql, bkh, MF(aqh, bkl, z)));
                    float ssk = swk[kt];
                    #pragma unroll
                    for (int r = 0; r < 4; r++) {
                        float l = fmaf(fmaf(sfv[r], htc[kt][r], 20.0f), swq[r] * ssk, -20.0f);
                        float p = __expf(l);
                        sum[r] += p;
                        scratch[(quad * 4 + r) * 40 + n2 * 16 + n16] = f2b(p * htc[kt][r]);
                    }
                }
                asm volatile("" ::: "memory");
                v8bf ap = *(const v8bfa*)(scratch + n16 * 40 + quad * 8);
                v8bf bg0 = *(const v8bfa*)(sm + G2T + n16 * 136 + ks * 32 + quad * 8);
                v8bf bg1 = *(const v8bfa*)(sm + G2T + (16 + n16) * 136 + ks * 32 + quad * 8);
                Ta0 = MF(ap, bg0, Ta0);
                Ta1 = MF(ap, bg1, Ta1);
                v8bf bh2 = *(const v8bfa*)(sm + H2T + hr * 128 + ks * 32 + quad * 8);
                ohl = MF(ap, bh2, ohl);
            }
            // ---- denominators + row factors ----
            float fac[4];
            #pragma unroll
            for (int r = 0; r < 4; r++) {
                float sc = sum[r];
                sc += __shfl_xor(sc, 1, 64);
                sc += __shfl_xor(sc, 2, 64);
                sc += __shfl_xor(sc, 4, 64);
                sc += __shfl_xor(sc, 8, 64);
                fac[r] = eqv[r] * 3.2659863237109f * __builtin_amdgcn_rcpf(sc);
            }
            #pragma unroll
            for (int r = 0; r < 4; r++) ohacc[r] += weqf[hd] * fac[r] * ohl[r];

            // ---- W2 refold (single-bf16): A=Wv[c][g], B=Wh[g][o] -> W2buf[o][c]
            asm volatile("" ::: "memory");
            {
                W8 vwh[2], hwh[2];
                #pragma unroll
                for (int mt = 0; mt < 2; mt++)
                    #pragma unroll
                    for (int j = 0; j < 8; j++) {
                        vwh[mt].u[j] = f2b(wv[(mt * 16 + n16) * 128 + (quad * 8 + j) * 4 + hd]);
                        hwh[mt].u[j] = f2b(wh[((quad * 8 + j) * 4 + hd) * 32 + mt * 16 + n16]);
                    }
                #pragma unroll
                for (int mt = 0; mt < 2; mt++)
                    #pragma unroll
                    for (int nt = 0; nt < 2; nt++) {
                        v4f c2 = MF(vwh[mt].v, hwh[nt].v, z);
                        u16x4 p;
                        p[0] = f2b(c2[0]); p[1] = f2b(c2[1]);
                        p[2] = f2b(c2[2]); p[3] = f2b(c2[3]);
                        *(u16x4a*)(scratch + (nt * 16 + n16) * 40 + mt * 16 + quad * 4) = p;
                    }
            }
            asm volatile("" ::: "memory");
            v8bf w20 = *(const v8bfa*)(scratch + n16 * 40 + quad * 8);
            v8bf w21 = *(const v8bfa*)(scratch + (16 + n16) * 40 + quad * 8);
            asm volatile("" ::: "memory");

            // ---- T (normalized) roundtrip -> og += T @ W2 ----
            #pragma unroll
            for (int r = 0; r < 4; r++) {
                scratch[(quad * 4 + r) * 40 + n16]      = f2b(Ta0[r] * fac[r]);
                scratch[(quad * 4 + r) * 40 + 16 + n16] = f2b(Ta1[r] * fac[r]);
            }
            asm volatile("" ::: "memory");
            v8bf aT = *(const v8bfa*)(scratch + n16 * 40 + quad * 8);
            asm volatile("" ::: "memory");
            og0 = MF(aT, w20, og0);
            og1 = MF(aT, w21, og1);
        }

        // ---- strip epilogue (f32 out) ----
        int qg = i * 128 + qb;
        #pragma unroll
        for (int r = 0; r < 4; r++) {
            outg[(size_t)(qg + r) * 32 + n16]      = og0[r] + bias0;
            outg[(size_t)(qg + r) * 32 + 16 + n16] = og1[r] + bias1;
        }
        if (n16 < 3) {
            #pragma unroll
            for (int r = 0; r < 4; r++)
                outh[(size_t)(qg + r) * 3 + n16] = ohacc[r];
        }
    }
}

extern "C" void kernel_launch(void* const* d_in, const int* in_sizes, int n_in,
                              void* d_out, int out_size, void* d_ws, size_t ws_size,
                              hipStream_t stream) {
    const float* g2  = (const float*)d_in[0];
    const float* h2  = (const float*)d_in[1];
    const float* sw  = (const float*)d_in[2];
    const float* wqk = (const float*)d_in[3];
    const float* wv  = (const float*)d_in[4];
    const float* wh  = (const float*)d_in[5];
    const float* bh  = (const float*)d_in[6];
    const float* weq = (const float*)d_in[7];
    const int*   nm  = (const int*)d_in[8];
    int nloc = in_sizes[0] / (128 * 32);   // 1024
    repformer_kernel<<<nloc, 256, 0, stream>>>(g2, h2, sw, wqk, wv, wh, bh, weq, nm, (float*)d_out);
}